// Round 1
// baseline (2875.095 us; speedup 1.0000x reference)
//
#include <hip/hip_runtime.h>
#include <math.h>

#define TP 16

// ---------------- workspace float offsets ----------------
static const size_t PE25_  = 0;         // 25*64
static const size_t PE24_  = 2048;      // 24*64
static const size_t SPAPE_ = 4096;      // 64*576
static const size_t PETOK_ = 40960;     // 576*128
static const size_t XBUF_  = 114688;    // 25*576
static const size_t BUF_   = 131072;    // 64*25*576
static const size_t T0_    = 1052672;
static const size_t T1_    = 1974272;
static const size_t BLK_   = 2895872;
static const size_t ATOK_  = 3817472;   // [x,64]
static const size_t TN_    = 4739072;   // [x,128] max
static const size_t QB_    = 6582272;
static const size_t KB_    = 8425472;
static const size_t VB_    = 10268672;
static const size_t AO_    = 12111872;
static const size_t STOK_  = 13955072;
static const size_t STOK2_ = 15798272;
static const size_t INP_   = TN_;       // alias (2304*1652)
static const size_t H0_    = VB_;       // alias (2304*320)
static const size_t H1_    = AO_;       // alias
static const size_t O2_    = STOK_;     // alias (2304*75)
static const size_t WS_FLOATS = 17641472;

// ---------------- small helpers ----------------
__device__ inline float pe_val(int pos, int c) {
  int j = c & 31;
  float freq = powf(10000.f, -2.f * (float)j / 64.f);
  float arg = (float)pos * freq;
  return (c < 32) ? sinf(arg) : cosf(arg);
}

__device__ inline float2 block_reduce2(float a, float b, float* scr, int nw) {
  #pragma unroll
  for (int off = 32; off > 0; off >>= 1) {
    a += __shfl_xor(a, off, 64);
    b += __shfl_xor(b, off, 64);
  }
  if (nw > 1) {
    int wid = threadIdx.x >> 6;
    if ((threadIdx.x & 63) == 0) { scr[wid*2] = a; scr[wid*2+1] = b; }
    __syncthreads();
    a = scr[0]; b = scr[1];
    for (int w = 1; w < nw; ++w) { a += scr[w*2]; b += scr[w*2+1]; }
    __syncthreads();
  }
  return make_float2(a, b);
}

// ---------------- setup kernels ----------------
__global__ void pe_tables_k(float* pe25, float* pe24) {
  int g = blockIdx.x * 256 + threadIdx.x;
  if (g < 25*64) pe25[g] = pe_val(g / 64, g & 63);
  else if (g < 25*64 + 24*64) { int q = g - 25*64; pe24[q] = pe_val(q / 64, q & 63); }
}

__global__ void spa_pe_k(const float* __restrict__ pe24, float* __restrict__ spa_pe) {
  int g = blockIdx.x * 256 + threadIdx.x;
  if (g >= 64*576) return;
  int c = g / 576, hw = g % 576, h = hw / 24, w = hw % 24;
  spa_pe[g] = 0.5f * (pe24[h*64 + c] + pe24[w*64 + c]);
}

__global__ void rearr_k(const float* __restrict__ lr, float* __restrict__ X) {
  int g = blockIdx.x * 256 + threadIdx.x;
  if (g >= 14400) return;
  int a = g / 576, hw = g % 576, h = hw / 24, w = hw % 24;
  int a1 = a / 5, a2 = a % 5;
  X[g] = lr[(a1*24 + h)*120 + a2*24 + w];
}

// ---------------- conv 3x3 (pad 1), per-view ----------------
// out[o] for 12 consecutive w positions of one row of one view.
// in addr  = a*isa + c*isc + hw*ishw ; out addr = a*osa + o*oso + hw*oshw
// mode: 0 none, 1 lrelu(0.2), 2 lrelu + residual
__global__ void conv3x3_k(const float* __restrict__ in, long isa, long isc, long ishw,
                          const float* __restrict__ W,
                          const float* __restrict__ res, long rsa, long rso, long rshw,
                          float* __restrict__ out, long osa, long oso, long oshw,
                          int IC, int OC, int mode) {
  int b = blockIdx.x;
  int a = b / 48; int r = b % 48; int h = r >> 1; int w0 = (r & 1) * 12;
  extern __shared__ float patch[];  // [IC][3][14]
  int n = IC * 42;
  for (int idx = threadIdx.x; idx < n; idx += blockDim.x) {
    int cidx = idx / 42; int rr = idx % 42; int i = rr / 14; int col = rr % 14;
    int h2 = h + i - 1; int w2 = w0 + col - 1;
    float v = 0.f;
    if ((unsigned)h2 < 24u && (unsigned)w2 < 24u)
      v = in[a*isa + cidx*isc + (long)(h2*24 + w2)*ishw];
    patch[idx] = v;
  }
  __syncthreads();
  int o = threadIdx.x;
  const float* wr = W + (long)o * IC * 9;
  float acc[12];
  #pragma unroll
  for (int p = 0; p < 12; ++p) acc[p] = 0.f;
  for (int cidx = 0; cidx < IC; ++cidx) {
    #pragma unroll
    for (int i = 0; i < 3; ++i) {
      const float* pr = patch + (cidx*3 + i)*14;
      #pragma unroll
      for (int j = 0; j < 3; ++j) {
        float wv = wr[cidx*9 + i*3 + j];
        #pragma unroll
        for (int p = 0; p < 12; ++p) acc[p] = fmaf(pr[j + p], wv, acc[p]);
      }
    }
  }
  #pragma unroll
  for (int p = 0; p < 12; ++p) {
    float v = acc[p];
    if (mode >= 1) v = v > 0.f ? v : 0.2f * v;
    long hw = h*24 + w0 + p;
    if (mode == 2) v += res[a*rsa + (long)o*rso + hw*rshw];
    out[a*osa + (long)o*oso + hw*oshw] = v;
  }
}

// ---------------- layernorm (+PE) ----------------
// in addr = x*ixs + c*ics ; pe addr = pidx*pxs + c*pcs, pidx = (mode? x%576 : x/576)
__global__ void ln_k(const float* __restrict__ in, long ixs, long ics,
                     const float* __restrict__ pe, long pxs, long pcs, int pe_mode,
                     const float* __restrict__ g, const float* __restrict__ b,
                     float* __restrict__ outp, int D) {
  __shared__ float scr[8];
  int x = blockIdx.x; int c = threadIdx.x; int nw = blockDim.x >> 6;
  int pidx = pe_mode ? (x % 576) : (x / 576);
  float v = in[(long)x*ixs + (long)c*ics] + pe[(long)pidx*pxs + (long)c*pcs];
  float2 s = block_reduce2(v, v*v, scr, nw);
  float mean = s.x / D;
  float var = s.y / D - mean*mean;
  outp[(long)x*D + c] = (v - mean) * rsqrtf(var + 1e-5f) * g[c] + b[c];
}

// ---------------- fused QKV (q,k from tn; v from tok) ----------------
__global__ void qkv_k(const float* __restrict__ tn,
                      const float* __restrict__ tokbase, long txs, long tcs,
                      const float* __restrict__ inw,
                      float* __restrict__ qb, float* __restrict__ kb, float* __restrict__ vb,
                      int D) {
  extern __shared__ float lds[];
  float* ltn = lds; float* ltok = lds + TP*D;
  long x0 = (long)blockIdx.x * TP;
  int c = threadIdx.x;
  for (int p = 0; p < TP; ++p) {
    long x = x0 + p;
    ltn[p*D + c] = tn[x*D + c];
    ltok[p*D + c] = tokbase[x*txs + (long)c*tcs];
  }
  __syncthreads();
  const float* wq = inw + (long)c*D;
  const float* wk = inw + (long)(D + c)*D;
  const float* wv = inw + (long)(2*D + c)*D;
  float aq[TP], ak[TP], av[TP];
  #pragma unroll
  for (int p = 0; p < TP; ++p) { aq[p]=0.f; ak[p]=0.f; av[p]=0.f; }
  for (int d = 0; d < D; ++d) {
    float q_ = wq[d], k_ = wk[d], v_ = wv[d];
    #pragma unroll
    for (int p = 0; p < TP; ++p) {
      float tv = ltn[p*D + d];
      aq[p] = fmaf(tv, q_, aq[p]);
      ak[p] = fmaf(tv, k_, ak[p]);
      av[p] = fmaf(ltok[p*D + d], v_, av[p]);
    }
  }
  for (int p = 0; p < TP; ++p) {
    long x = x0 + p;
    qb[x*D + c] = aq[p]; kb[x*D + c] = ak[p]; vb[x*D + c] = av[p];
  }
}

// ---------------- angular attention (seq=25, nh=8, dh=8) ----------------
__global__ void attn_ang_k(const float* __restrict__ qb, const float* __restrict__ kb,
                           const float* __restrict__ vb, float* __restrict__ ao) {
  int hw = blockIdx.x;
  __shared__ float lq[25*64], lk[25*64], lv[25*64];
  for (int idx = threadIdx.x; idx < 25*64; idx += 256) {
    int a = idx >> 6, c = idx & 63;
    long src = (long)(a*576 + hw)*64 + c;
    lq[idx] = qb[src]; lk[idx] = kb[src]; lv[idx] = vb[src];
  }
  __syncthreads();
  int t = threadIdx.x;
  if (t >= 200) return;
  int l = t / 8, head = t & 7;
  const float* q = lq + l*64 + head*8;
  float s[25]; float mx = -1e30f;
  #pragma unroll
  for (int m = 0; m < 25; ++m) {
    const float* kk = lk + m*64 + head*8;
    float acc = 0.f;
    #pragma unroll
    for (int d = 0; d < 8; ++d) acc = fmaf(q[d], kk[d], acc);
    acc *= 0.3535533905932738f;
    s[m] = acc; mx = fmaxf(mx, acc);
  }
  float sum = 0.f;
  #pragma unroll
  for (int m = 0; m < 25; ++m) { s[m] = expf(s[m] - mx); sum += s[m]; }
  float inv = 1.f / sum;
  #pragma unroll
  for (int d = 0; d < 8; ++d) {
    float acc = 0.f;
    #pragma unroll
    for (int m = 0; m < 25; ++m) acc = fmaf(s[m], lv[m*64 + head*8 + d], acc);
    ao[(long)(l*576 + hw)*64 + head*8 + d] = acc * inv;
  }
}

// ---------------- spatial attention (seq=576, 5x5 window, nh=8, dh=16) ----------------
__global__ void attn_spa_k(const float* __restrict__ qb, const float* __restrict__ kb,
                           const float* __restrict__ vb, float* __restrict__ ao) {
  int g = blockIdx.x * 256 + threadIdx.x;
  if (g >= 25*576*8) return;
  int head = g & 7; int x = g >> 3;
  int a = x / 576, hw = x % 576, h = hw / 24, w = hw % 24;
  float qr[16];
  const float* qp = qb + (long)x*128 + head*16;
  #pragma unroll
  for (int d = 0; d < 16; ++d) qr[d] = qp[d];
  float s[25]; float mx = -1e30f;
  #pragma unroll
  for (int i = 0; i < 25; ++i) {
    int h2 = h + i/5 - 2, w2 = w + i%5 - 2;
    float sc = -1e30f;
    if (h2 >= 0 && h2 < 24 && w2 >= 0 && w2 < 24) {
      const float* kp = kb + ((long)(a*576 + h2*24 + w2)*128 + head*16);
      sc = 0.f;
      #pragma unroll
      for (int d = 0; d < 16; ++d) sc = fmaf(qr[d], kp[d], sc);
      sc *= 0.25f;
    }
    s[i] = sc; mx = fmaxf(mx, sc);
  }
  float sum = 0.f;
  #pragma unroll
  for (int i = 0; i < 25; ++i) {
    float e = (s[i] > -1e29f) ? expf(s[i] - mx) : 0.f;
    s[i] = e; sum += e;
  }
  float inv = 1.f / sum;
  float acc[16];
  #pragma unroll
  for (int d = 0; d < 16; ++d) acc[d] = 0.f;
  #pragma unroll
  for (int i = 0; i < 25; ++i) {
    if (s[i] > 0.f) {
      int h2 = h + i/5 - 2, w2 = w + i%5 - 2;
      const float* vp = vb + ((long)(a*576 + h2*24 + w2)*128 + head*16);
      #pragma unroll
      for (int d = 0; d < 16; ++d) acc[d] = fmaf(s[i], vp[d], acc[d]);
    }
  }
  float* op = ao + (long)x*128 + head*16;
  #pragma unroll
  for (int d = 0; d < 16; ++d) op[d] = acc[d] * inv;
}

// ---------------- generic linear: out = act(in @ W^T + bias) (+res) ----------------
// in: [X,K] k-contig; out addr = x*oxs + c*ocs; res addr = x*rxs + c*rcs
__global__ void linear_k(const float* __restrict__ in, const float* __restrict__ W,
                         const float* __restrict__ bias,
                         const float* __restrict__ res, long rxs, long rcs,
                         float* __restrict__ out, long oxs, long ocs,
                         int K, int O, int act) {
  extern __shared__ float tile[];  // [TP][256]
  const int KT = 256;
  long x0 = (long)blockIdx.x * TP;
  int c = threadIdx.x;
  float acc[TP];
  #pragma unroll
  for (int p = 0; p < TP; ++p) acc[p] = 0.f;
  for (int k0 = 0; k0 < K; k0 += KT) {
    int kt = min(KT, K - k0);
    __syncthreads();
    for (int idx = threadIdx.x; idx < TP*kt; idx += blockDim.x) {
      int p = idx / kt, kk = idx % kt;
      tile[p*KT + kk] = in[(x0 + p)*K + k0 + kk];
    }
    __syncthreads();
    if (c < O) {
      const float* wr = W + (long)c*K + k0;
      for (int kk = 0; kk < kt; ++kk) {
        float wv = wr[kk];
        #pragma unroll
        for (int p = 0; p < TP; ++p) acc[p] = fmaf(tile[p*KT + kk], wv, acc[p]);
      }
    }
  }
  if (c < O) {
    float b = bias ? bias[c] : 0.f;
    for (int p = 0; p < TP; ++p) {
      long x = x0 + p;
      float v = acc[p] + b;
      if (act == 1) v = fmaxf(v, 0.f);
      if (res) v += res[x*rxs + (long)c*rcs];
      out[x*oxs + (long)c*ocs] = v;
    }
  }
}

// ---------------- fused FFN: tok = W2 @ relu(W1 @ LN(tok)) + tok (in-place) ----------------
__global__ void ffn_k(float* __restrict__ tok,
                      const float* __restrict__ g, const float* __restrict__ bb,
                      const float* __restrict__ w1, const float* __restrict__ w2, int D) {
  extern __shared__ float lds[];
  float* xr  = lds;               // [TP][D]
  float* hh  = lds + TP*D;        // [TP][2D]
  float* scr = hh + TP*2*D;       // [8]
  int c = threadIdx.x, nw = blockDim.x >> 6;
  long x0 = (long)blockIdx.x * TP;
  for (int p = 0; p < TP; ++p) xr[p*D + c] = tok[(x0 + p)*D + c];
  __syncthreads();
  float gc = g[c], bc = bb[c];
  for (int p = 0; p < TP; ++p) {
    float v = xr[p*D + c];
    float2 sred = block_reduce2(v, v*v, scr, nw);
    float mean = sred.x / D;
    float var = sred.y / D - mean*mean;
    xr[p*D + c] = (v - mean) * rsqrtf(var + 1e-5f) * gc + bc;
  }
  __syncthreads();
  float accA[TP], accB[TP];
  #pragma unroll
  for (int p = 0; p < TP; ++p) { accA[p] = 0.f; accB[p] = 0.f; }
  const float* w1a = w1 + (long)c*D;
  const float* w1b = w1 + (long)(c + D)*D;
  for (int d = 0; d < D; ++d) {
    float wa = w1a[d], wb = w1b[d];
    #pragma unroll
    for (int p = 0; p < TP; ++p) {
      float xv = xr[p*D + d];
      accA[p] = fmaf(xv, wa, accA[p]);
      accB[p] = fmaf(xv, wb, accB[p]);
    }
  }
  for (int p = 0; p < TP; ++p) {
    hh[p*2*D + c] = fmaxf(accA[p], 0.f);
    hh[p*2*D + D + c] = fmaxf(accB[p], 0.f);
  }
  __syncthreads();
  float acc[TP];
  #pragma unroll
  for (int p = 0; p < TP; ++p) acc[p] = 0.f;
  const float* w2r = w2 + (long)c*2*D;
  for (int j = 0; j < 2*D; ++j) {
    float wv = w2r[j];
    #pragma unroll
    for (int p = 0; p < TP; ++p) acc[p] = fmaf(hh[p*2*D + j], wv, acc[p]);
  }
  for (int p = 0; p < TP; ++p) {
    long idx = (x0 + p)*D + c;
    tok[idx] = acc[p] + tok[idx];
  }
}

__global__ void add_k(float* __restrict__ a, const float* __restrict__ b, int n) {
  int g = blockIdx.x * 256 + threadIdx.x;
  if (g < n) a[g] += b[g];
}

// ---------------- upsample + concat -> imp MLP input ----------------
__global__ void build_inp_k(const float* __restrict__ buf, const float* __restrict__ coord,
                            float* __restrict__ inp) {
  long g = (long)blockIdx.x * 256 + threadIdx.x;
  if (g >= 2304L*1652) return;
  int p = (int)(g / 1652); int k = (int)(g % 1652);
  int hh = p / 48, ww = p % 48;
  float v;
  if (k < 1600) {
    int a = k >> 6, c = k & 63;
    float sh = hh*0.5f - 0.25f; float sw = ww*0.5f - 0.25f;
    int h0 = (int)floorf(sh); float fh = sh - h0;
    int w0 = (int)floorf(sw); float fw = sw - w0;
    int h0c = max(h0, 0), h1c = min(h0 + 1, 23);
    int w0c = max(w0, 0), w1c = min(w0 + 1, 23);
    const float* img = buf + (long)c*14400 + a*576;
    float v00 = img[h0c*24 + w0c], v01 = img[h0c*24 + w1c];
    float v10 = img[h1c*24 + w0c], v11 = img[h1c*24 + w1c];
    v = (1.f - fh)*((1.f - fw)*v00 + fw*v01) + fh*((1.f - fw)*v10 + fw*v11);
  } else if (k < 1602) {
    int d = k - 1600;
    float co = coord[p*2 + d];
    float cc = fminf(fmaxf(co + 1e-6f, -1.f + 1e-6f), 1.f - 1e-6f);
    float ix = rintf(((cc + 1.f)*24.f - 1.f)*0.5f);
    ix = fminf(fmaxf(ix, 0.f), 23.f);
    float q = -1.f + (2.f*ix + 1.f)/24.f;
    v = (co - q)*24.f;
  } else {
    int idx = k - 1602; int pair = idx >> 1; int t = idx & 1;
    int i = pair / 5, j = pair % 5;
    v = 0.5f + (float)(t ? j : i);
  }
  inp[g] = v;
}

__global__ void out_rearr_k(const float* __restrict__ o2, float* __restrict__ out) {
  int g = blockIdx.x * 256 + threadIdx.x;
  if (g >= 172800) return;
  int ch = g / 57600; int r = g % 57600;
  int row = r / 240, col = r % 240;
  int a1 = row / 48, hh = row % 48, a2 = col / 48, ww = col % 48;
  out[g] = o2[(hh*48 + ww)*75 + (a1*5 + a2)*3 + ch];
}

// ---------------- host launch ----------------
extern "C" void kernel_launch(void* const* d_in, const int* in_sizes, int n_in,
                              void* d_out, int out_size, void* d_ws, size_t ws_size,
                              hipStream_t stream) {
  (void)in_sizes; (void)n_in; (void)out_size;
  if (ws_size < (size_t)WS_FLOATS * 4) return;
  float* ws = (float*)d_ws;

  const float* lr       = (const float*)d_in[0];
  const float* coord    = (const float*)d_in[1];
  const float* conv0_w  = (const float*)d_in[2];
  const float* convi_w  = (const float*)d_in[3];
  const float* ang_ln_g = (const float*)d_in[4];
  const float* ang_ln_b = (const float*)d_in[5];
  const float* ang_in   = (const float*)d_in[6];
  const float* ang_out  = (const float*)d_in[7];
  const float* ang_ff_g = (const float*)d_in[8];
  const float* ang_ff_b = (const float*)d_in[9];
  const float* ang_w1   = (const float*)d_in[10];
  const float* ang_w2   = (const float*)d_in[11];
  const float* spa_mlp  = (const float*)d_in[12];
  const float* spa_ln_g = (const float*)d_in[13];
  const float* spa_ln_b = (const float*)d_in[14];
  const float* spa_in   = (const float*)d_in[15];
  const float* spa_out  = (const float*)d_in[16];
  const float* spa_ff_g = (const float*)d_in[17];
  const float* spa_ff_b = (const float*)d_in[18];
  const float* spa_w1   = (const float*)d_in[19];
  const float* spa_w2   = (const float*)d_in[20];
  const float* spa_lin  = (const float*)d_in[21];
  const float* imp_w0   = (const float*)d_in[22];
  const float* imp_b0   = (const float*)d_in[23];
  const float* imp_w1   = (const float*)d_in[24];
  const float* imp_b1   = (const float*)d_in[25];
  const float* imp_w2   = (const float*)d_in[26];
  const float* imp_b2   = (const float*)d_in[27];

  float* pe25 = ws + PE25_;  float* pe24 = ws + PE24_;  float* spa_pe = ws + SPAPE_;
  float* petok = ws + PETOK_; float* X = ws + XBUF_;
  float* buf = ws + BUF_;   float* t0 = ws + T0_;   float* t1 = ws + T1_;
  float* blk = ws + BLK_;   float* atok = ws + ATOK_; float* tn = ws + TN_;
  float* qb = ws + QB_;     float* kb = ws + KB_;   float* vb = ws + VB_;
  float* ao = ws + AO_;     float* stok = ws + STOK_; float* stok2 = ws + STOK2_;
  float* inp = ws + INP_;   float* h0 = ws + H0_;   float* h1 = ws + H1_;
  float* o2 = ws + O2_;

  pe_tables_k<<<13, 256, 0, stream>>>(pe25, pe24);
  spa_pe_k<<<144, 256, 0, stream>>>(pe24, spa_pe);
  rearr_k<<<57, 256, 0, stream>>>(lr, X);

  // conv0 (1->64) then 3x (64->64, lrelu), residual add into buf
  conv3x3_k<<<1200, 64, 1*42*4, stream>>>(X, 576, 0, 1, conv0_w,
      nullptr, 0, 0, 0, buf, 576, 14400, 1, 1, 64, 0);
  conv3x3_k<<<1200, 64, 64*42*4, stream>>>(buf, 576, 14400, 1, convi_w,
      nullptr, 0, 0, 0, t0, 576, 14400, 1, 64, 64, 1);
  conv3x3_k<<<1200, 64, 64*42*4, stream>>>(t0, 576, 14400, 1, convi_w + 64*64*9,
      nullptr, 0, 0, 0, t1, 576, 14400, 1, 64, 64, 1);
  conv3x3_k<<<1200, 64, 64*42*4, stream>>>(t1, 576, 14400, 1, convi_w + 2*64*64*9,
      buf, 576, 14400, 1, buf, 576, 14400, 1, 64, 64, 2);

  for (int l = 0; l < 4; ++l) {
    const float* blkr = (l == 0) ? buf : blk;
    // ---- AngTrans ----
    ln_k<<<14400, 64, 0, stream>>>(blkr, 1, 14400, pe25, 64, 1, 0,
        ang_ln_g + l*64, ang_ln_b + l*64, tn, 64);
    qkv_k<<<900, 64, 2*TP*64*4, stream>>>(tn, blkr, 1, 14400, ang_in + l*192*64,
        qb, kb, vb, 64);
    attn_ang_k<<<576, 256, 0, stream>>>(qb, kb, vb, ao);
    linear_k<<<900, 64, TP*256*4, stream>>>(ao, ang_out + l*64*64, nullptr,
        blkr, 1, 14400, atok, 64, 1, 64, 64, 0);
    ffn_k<<<900, 64, (TP*64 + TP*128 + 8)*4, stream>>>(atok,
        ang_ff_g + l*64, ang_ff_b + l*64, ang_w1 + l*128*64, ang_w2 + l*64*128, 64);
    // ---- SpaTrans ----
    conv3x3_k<<<48, 128, 64*42*4, stream>>>(spa_pe, 0, 576, 1, spa_mlp + l*128*576,
        nullptr, 0, 0, 0, petok, 0, 1, 128, 64, 128, 0);
    conv3x3_k<<<1200, 128, 64*42*4, stream>>>(atok, 36864, 1, 64, spa_mlp + l*128*576,
        nullptr, 0, 0, 0, stok, 73728, 1, 128, 64, 128, 0);
    ln_k<<<14400, 128, 0, stream>>>(stok, 128, 1, petok, 128, 1, 1,
        spa_ln_g + l*128, spa_ln_b + l*128, tn, 128);
    qkv_k<<<900, 128, 2*TP*128*4, stream>>>(tn, stok, 128, 1, spa_in + l*384*128,
        qb, kb, vb, 128);
    attn_spa_k<<<450, 256, 0, stream>>>(qb, kb, vb, ao);
    linear_k<<<900, 128, TP*256*4, stream>>>(ao, spa_out + l*128*128, nullptr,
        stok, 128, 1, stok2, 128, 1, 128, 128, 0);
    ffn_k<<<900, 128, (TP*128 + TP*256 + 8)*4, stream>>>(stok2,
        spa_ff_g + l*128, spa_ff_b + l*128, spa_w1 + l*256*128, spa_w2 + l*128*256, 128);
    linear_k<<<900, 64, TP*256*4, stream>>>(stok2, spa_lin + l*64*128, nullptr,
        nullptr, 0, 0, blk, 1, 14400, 128, 64, 0);
  }

  add_k<<<3600, 256, 0, stream>>>(buf, blk, 921600);
  build_inp_k<<<14868, 256, 0, stream>>>(buf, coord, inp);
  linear_k<<<144, 320, TP*256*4, stream>>>(inp, imp_w0, imp_b0, nullptr, 0, 0,
      h0, 320, 1, 1652, 320, 1);
  linear_k<<<144, 320, TP*256*4, stream>>>(h0, imp_w1, imp_b1, nullptr, 0, 0,
      h1, 320, 1, 320, 320, 1);
  linear_k<<<144, 128, TP*256*4, stream>>>(h1, imp_w2, imp_b2, nullptr, 0, 0,
      o2, 75, 1, 320, 75, 0);
  out_rearr_k<<<675, 256, 0, stream>>>(o2, (float*)d_out);
}

// Round 2
// 1463.772 us; speedup vs baseline: 1.9642x; 1.9642x over previous
//
#include <hip/hip_runtime.h>
#include <math.h>

// ---------------- workspace float offsets ----------------
static const size_t PE25_  = 0;         // 25*64
static const size_t PE24_  = 1600;      // 24*64
static const size_t SPAPE_ = 3136;      // [576][64]
static const size_t PETOK_ = 40000;     // [576][128]
static const size_t X_     = 113728;    // [25][576]
static const size_t BUF_   = 131072;    // [14400][64]
static const size_t BLK_   = 1052672;   // [14400][64]
static const size_t ATOK_  = 1974272;   // [14400][64]
static const size_t STOK_  = 2895872;   // [14400][128]
static const size_t STOK2_ = 4739072;   // [14400][128]
static const size_t TN_    = 6582272;   // [14400][128]
static const size_t AO_    = 8425472;   // [14400][128]; also hbuf (up to [14400][256])
static const size_t QKV_   = 10268672;  // [14400][384]; also t0,t1, inp
static const size_t WS_FLOATS = 15798272;
static const size_t T0_ = QKV_;
static const size_t T1_ = QKV_ + 921600;
static const size_t HB_ = AO_;
static const size_t INP_ = QKV_;        // [2304][1652]
static const size_t H0_ = STOK_;        // [2304][320]
static const size_t H1_ = STOK2_;
static const size_t O2_ = TN_;          // [2304][75]

// ---------------- setup ----------------
__device__ inline float pe_val(int pos, int c) {
  int j = c & 31;
  float freq = powf(10000.f, -2.f * (float)j / 64.f);
  float arg = (float)pos * freq;
  return (c < 32) ? sinf(arg) : cosf(arg);
}

__global__ void pe_tables_k(float* pe25, float* pe24) {
  int g = blockIdx.x * 256 + threadIdx.x;
  if (g < 25*64) pe25[g] = pe_val(g / 64, g & 63);
  else if (g < 25*64 + 24*64) { int q = g - 25*64; pe24[q] = pe_val(q / 64, q & 63); }
}

__global__ void spa_pe_k(const float* __restrict__ pe24, float* __restrict__ spa_pe) {
  int g = blockIdx.x * 256 + threadIdx.x;
  if (g >= 576*64) return;
  int hw = g >> 6, c = g & 63; int h = hw / 24, w = hw % 24;
  spa_pe[g] = 0.5f * (pe24[h*64 + c] + pe24[w*64 + c]);
}

__global__ void rearr_k(const float* __restrict__ lr, float* __restrict__ X) {
  int g = blockIdx.x * 256 + threadIdx.x;
  if (g >= 14400) return;
  int a = g / 576, hw = g % 576, h = hw / 24, w = hw % 24;
  int a1 = a / 5, a2 = a % 5;
  X[g] = lr[(a1*24 + h)*120 + a2*24 + w];
}

// ---------------- conv 3x3 (pad 1), per-view, 12-wide strips ----------------
// in addr = a*isa + c*isc + hw*ishw ; out addr = a*osa + o*oso + hw*oshw
// patch LDS layout: [IC][3][16] (cols 0..13 = w0-1 .. w0+12)
// mode: 0 none, 1 lrelu(0.2), 2 lrelu + residual
__global__ void conv3x3_k(const float* __restrict__ in, long isa, long isc, long ishw,
                          const float* __restrict__ W,
                          const float* __restrict__ res, long rsa, long rso, long rshw,
                          float* __restrict__ out, long osa, long oso, long oshw,
                          int IC, int OC, int mode) {
  int bq = blockIdx.x;
  int a = bq / 48; int r = bq % 48; int h = r >> 1; int w0 = (r & 1) * 12;
  extern __shared__ float patch[];  // IC*48
  int n = IC * 42;
  for (int idx = threadIdx.x; idx < n; idx += blockDim.x) {
    int c = idx % IC; int pos = idx / IC; int i = pos / 14; int col = pos % 14;
    int h2 = h + i - 1; int w2 = w0 + col - 1;
    float v = 0.f;
    if ((unsigned)h2 < 24u && (unsigned)w2 < 24u)
      v = in[a*isa + (long)c*isc + (long)(h2*24 + w2)*ishw];
    patch[(c*3 + i)*16 + col] = v;
  }
  __syncthreads();
  int o = threadIdx.x;
  if (o >= OC) return;
  const float* wr = W + (long)o * IC * 9;
  float acc[12];
  #pragma unroll
  for (int p = 0; p < 12; ++p) acc[p] = 0.f;
  for (int c = 0; c < IC; ++c) {
    #pragma unroll
    for (int i = 0; i < 3; ++i) {
      const float* pr = &patch[(c*3 + i)*16];
      float rowv[16];
      *(float4*)&rowv[0]  = *(const float4*)&pr[0];
      *(float4*)&rowv[4]  = *(const float4*)&pr[4];
      *(float4*)&rowv[8]  = *(const float4*)&pr[8];
      *(float4*)&rowv[12] = *(const float4*)&pr[12];
      float wv0 = wr[c*9 + i*3 + 0];
      float wv1 = wr[c*9 + i*3 + 1];
      float wv2 = wr[c*9 + i*3 + 2];
      #pragma unroll
      for (int p = 0; p < 12; ++p)
        acc[p] = fmaf(rowv[p], wv0, fmaf(rowv[p+1], wv1, fmaf(rowv[p+2], wv2, acc[p])));
    }
  }
  #pragma unroll
  for (int p = 0; p < 12; ++p) {
    float v = acc[p];
    if (mode >= 1) v = v > 0.f ? v : 0.2f * v;
    long hw = h*24 + w0 + p;
    if (mode == 2) v += res[a*rsa + (long)o*rso + hw*rshw];
    out[a*osa + (long)o*oso + hw*oshw] = v;
  }
}

// ---------------- layernorm (+optional PE), token-major, wave per token ----------------
// pe_mode: -1 none, 0 pidx=x/576, 1 pidx=x%576
__global__ void ln_k(const float* __restrict__ in, const float* __restrict__ pe,
                     int pe_mode, const float* __restrict__ g, const float* __restrict__ b,
                     float* __restrict__ outp, int D) {
  int x = blockIdx.x * 4 + (threadIdx.x >> 6);
  int lane = threadIdx.x & 63;
  int E = D >> 6;
  float v[2]; float s = 0.f, s2 = 0.f;
  int pidx = (pe_mode == 0) ? (x / 576) : (x % 576);
  for (int e = 0; e < E; ++e) {
    int c = e*64 + lane;
    float t = in[(long)x*D + c];
    if (pe_mode >= 0) t += pe[(long)pidx*D + c];
    v[e] = t; s += t; s2 = fmaf(t, t, s2);
  }
  #pragma unroll
  for (int off = 32; off; off >>= 1) {
    s += __shfl_xor(s, off, 64); s2 += __shfl_xor(s2, off, 64);
  }
  float mean = s / D;
  float var = s2 / D - mean*mean;
  float rs = rsqrtf(var + 1e-5f);
  for (int e = 0; e < E; ++e) {
    int c = e*64 + lane;
    outp[(long)x*D + c] = (v[e] - mean) * rs * g[c] + b[c];
  }
}

// ---------------- tiled GEMM: out = act(A @ W^T + bias) + res ----------------
// A,A2: [M][K] row-major (block uses A2 when n0>=nsplit); W: [N][K]; out,res: [M][N]
__global__ void gemm_k(const float* __restrict__ A, const float* A2, int nsplit,
                       const float* __restrict__ W, const float* __restrict__ bias,
                       const float* res, float* out,
                       int M, int N, int K, int act) {
  __shared__ float As[32][36], Bs[32][36];
  int n0 = blockIdx.x * 32, m0 = blockIdx.y * 32;
  const float* Ap = (n0 >= nsplit) ? A2 : A;
  int t = threadIdx.x;
  int tx = t & 15, ty = t >> 4;
  int r = t >> 3, c4 = (t & 7) << 2;
  float acc00 = 0.f, acc01 = 0.f, acc10 = 0.f, acc11 = 0.f;
  const float* arow = Ap + (long)(m0 + r) * K;
  const float* brow = W + (long)(n0 + r) * K;
  bool bok = (n0 + r) < N;
  for (int k0 = 0; k0 < K; k0 += 32) {
    float4 av = make_float4(0.f,0.f,0.f,0.f), bv = make_float4(0.f,0.f,0.f,0.f);
    if (k0 + c4 < K) {
      av = *(const float4*)&arow[k0 + c4];
      if (bok) bv = *(const float4*)&brow[k0 + c4];
    }
    __syncthreads();
    *(float4*)&As[r][c4] = av;
    *(float4*)&Bs[r][c4] = bv;
    __syncthreads();
    #pragma unroll
    for (int kk = 0; kk < 32; kk += 2) {
      float2 a0 = *(const float2*)&As[ty][kk];
      float2 a1 = *(const float2*)&As[ty + 16][kk];
      float2 b0 = *(const float2*)&Bs[tx][kk];
      float2 b1 = *(const float2*)&Bs[tx + 16][kk];
      acc00 = fmaf(a0.x, b0.x, fmaf(a0.y, b0.y, acc00));
      acc01 = fmaf(a0.x, b1.x, fmaf(a0.y, b1.y, acc01));
      acc10 = fmaf(a1.x, b0.x, fmaf(a1.y, b0.y, acc10));
      acc11 = fmaf(a1.x, b1.x, fmaf(a1.y, b1.y, acc11));
    }
  }
  float accs[2][2] = {{acc00, acc01}, {acc10, acc11}};
  #pragma unroll
  for (int i = 0; i < 2; ++i) {
    int rr = m0 + ty + i*16;
    #pragma unroll
    for (int j = 0; j < 2; ++j) {
      int cc = n0 + tx + j*16;
      if (cc < N) {
        float vv = accs[i][j];
        if (bias) vv += bias[cc];
        if (act == 1) vv = fmaxf(vv, 0.f);
        if (res) vv += res[(long)rr*N + cc];
        out[(long)rr*N + cc] = vv;
      }
    }
  }
}

// ---------------- angular attention (seq=25, nh=8, dh=8) ----------------
// qkv: [x][192] (q:0-63, k:64-127, v:128-191), x = a*576+hw; ao: [x][64]
__global__ void attn_ang_k(const float* __restrict__ qkv, float* __restrict__ ao) {
  int hw = blockIdx.x;
  __shared__ float lds[25*192];
  for (int idx = threadIdx.x; idx < 25*192; idx += 256) {
    int a = idx / 192, c = idx % 192;
    lds[idx] = qkv[(long)(a*576 + hw)*192 + c];
  }
  __syncthreads();
  int t = threadIdx.x;
  if (t >= 200) return;
  int l = t / 8, head = t & 7;
  const float* q = lds + l*192 + head*8;
  float s[25]; float mx = -1e30f;
  #pragma unroll
  for (int m = 0; m < 25; ++m) {
    const float* kk = lds + m*192 + 64 + head*8;
    float acc = 0.f;
    #pragma unroll
    for (int d = 0; d < 8; ++d) acc = fmaf(q[d], kk[d], acc);
    acc *= 0.3535533905932738f;
    s[m] = acc; mx = fmaxf(mx, acc);
  }
  float sum = 0.f;
  #pragma unroll
  for (int m = 0; m < 25; ++m) { s[m] = expf(s[m] - mx); sum += s[m]; }
  float inv = 1.f / sum;
  #pragma unroll
  for (int d = 0; d < 8; ++d) {
    float acc = 0.f;
    #pragma unroll
    for (int m = 0; m < 25; ++m) acc = fmaf(s[m], lds[m*192 + 128 + head*8 + d], acc);
    ao[(long)(l*576 + hw)*64 + head*8 + d] = acc * inv;
  }
}

// ---------------- spatial attention (5x5 window, nh=8, dh=16) ----------------
// qkv: [x][384] (q:0-127, k:128-255, v:256-383); ao: [x][128]
__global__ void attn_spa_k(const float* __restrict__ qkv, float* __restrict__ ao) {
  int g = blockIdx.x * 256 + threadIdx.x;
  if (g >= 14400*8) return;
  int head = g & 7; int x = g >> 3;
  int a = x / 576, hw = x % 576, h = hw / 24, w = hw % 24;
  float qr[16];
  const float* qp = qkv + (long)x*384 + head*16;
  #pragma unroll
  for (int d = 0; d < 16; ++d) qr[d] = qp[d];
  float s[25]; float mx = -1e30f;
  #pragma unroll
  for (int i = 0; i < 25; ++i) {
    int h2 = h + i/5 - 2, w2 = w + i%5 - 2;
    float sc = -1e30f;
    if (h2 >= 0 && h2 < 24 && w2 >= 0 && w2 < 24) {
      const float* kp = qkv + (long)(a*576 + h2*24 + w2)*384 + 128 + head*16;
      sc = 0.f;
      #pragma unroll
      for (int d = 0; d < 16; ++d) sc = fmaf(qr[d], kp[d], sc);
      sc *= 0.25f;
    }
    s[i] = sc; mx = fmaxf(mx, sc);
  }
  float sum = 0.f;
  #pragma unroll
  for (int i = 0; i < 25; ++i) {
    float e = (s[i] > -1e29f) ? expf(s[i] - mx) : 0.f;
    s[i] = e; sum += e;
  }
  float inv = 1.f / sum;
  float acc[16];
  #pragma unroll
  for (int d = 0; d < 16; ++d) acc[d] = 0.f;
  #pragma unroll
  for (int i = 0; i < 25; ++i) {
    if (s[i] > 0.f) {
      int h2 = h + i/5 - 2, w2 = w + i%5 - 2;
      const float* vp = qkv + (long)(a*576 + h2*24 + w2)*384 + 256 + head*16;
      #pragma unroll
      for (int d = 0; d < 16; ++d) acc[d] = fmaf(s[i], vp[d], acc[d]);
    }
  }
  float* op = ao + (long)x*128 + head*16;
  #pragma unroll
  for (int d = 0; d < 16; ++d) op[d] = acc[d] * inv;
}

__global__ void add_k(float* __restrict__ a, const float* __restrict__ b, int n) {
  int g = blockIdx.x * 256 + threadIdx.x;
  if (g < n) a[g] += b[g];
}

// ---------------- upsample + concat -> imp MLP input (buf token-major) ----------------
__global__ void build_inp_k(const float* __restrict__ buf, const float* __restrict__ coord,
                            float* __restrict__ inp) {
  long g = (long)blockIdx.x * 256 + threadIdx.x;
  if (g >= 2304L*1652) return;
  int p = (int)(g / 1652); int k = (int)(g % 1652);
  int hh = p / 48, ww = p % 48;
  float v;
  if (k < 1600) {
    int a = k >> 6, c = k & 63;
    float sh = hh*0.5f - 0.25f; float sw = ww*0.5f - 0.25f;
    int h0 = (int)floorf(sh); float fh = sh - h0;
    int w0 = (int)floorf(sw); float fw = sw - w0;
    int h0c = max(h0, 0), h1c = min(h0 + 1, 23);
    int w0c = max(w0, 0), w1c = min(w0 + 1, 23);
    long base = (long)a*576;
    float v00 = buf[(base + h0c*24 + w0c)*64 + c], v01 = buf[(base + h0c*24 + w1c)*64 + c];
    float v10 = buf[(base + h1c*24 + w0c)*64 + c], v11 = buf[(base + h1c*24 + w1c)*64 + c];
    v = (1.f - fh)*((1.f - fw)*v00 + fw*v01) + fh*((1.f - fw)*v10 + fw*v11);
  } else if (k < 1602) {
    int d = k - 1600;
    float co = coord[p*2 + d];
    float cc = fminf(fmaxf(co + 1e-6f, -1.f + 1e-6f), 1.f - 1e-6f);
    float ix = rintf(((cc + 1.f)*24.f - 1.f)*0.5f);
    ix = fminf(fmaxf(ix, 0.f), 23.f);
    float q = -1.f + (2.f*ix + 1.f)/24.f;
    v = (co - q)*24.f;
  } else {
    int idx = k - 1602; int pair = idx >> 1; int t = idx & 1;
    int i = pair / 5, j = pair % 5;
    v = 0.5f + (float)(t ? j : i);
  }
  inp[g] = v;
}

__global__ void out_rearr_k(const float* __restrict__ o2, float* __restrict__ out) {
  int g = blockIdx.x * 256 + threadIdx.x;
  if (g >= 172800) return;
  int ch = g / 57600; int r = g % 57600;
  int row = r / 240, col = r % 240;
  int a1 = row / 48, hh = row % 48, a2 = col / 48, ww = col % 48;
  out[g] = o2[(hh*48 + ww)*75 + (a1*5 + a2)*3 + ch];
}

// ---------------- host launch ----------------
extern "C" void kernel_launch(void* const* d_in, const int* in_sizes, int n_in,
                              void* d_out, int out_size, void* d_ws, size_t ws_size,
                              hipStream_t stream) {
  (void)in_sizes; (void)n_in; (void)out_size;
  if (ws_size < (size_t)WS_FLOATS * 4) return;
  float* ws = (float*)d_ws;

  const float* lr       = (const float*)d_in[0];
  const float* coord    = (const float*)d_in[1];
  const float* conv0_w  = (const float*)d_in[2];
  const float* convi_w  = (const float*)d_in[3];
  const float* ang_ln_g = (const float*)d_in[4];
  const float* ang_ln_b = (const float*)d_in[5];
  const float* ang_in   = (const float*)d_in[6];
  const float* ang_out  = (const float*)d_in[7];
  const float* ang_ff_g = (const float*)d_in[8];
  const float* ang_ff_b = (const float*)d_in[9];
  const float* ang_w1   = (const float*)d_in[10];
  const float* ang_w2   = (const float*)d_in[11];
  const float* spa_mlp  = (const float*)d_in[12];
  const float* spa_ln_g = (const float*)d_in[13];
  const float* spa_ln_b = (const float*)d_in[14];
  const float* spa_in   = (const float*)d_in[15];
  const float* spa_out  = (const float*)d_in[16];
  const float* spa_ff_g = (const float*)d_in[17];
  const float* spa_ff_b = (const float*)d_in[18];
  const float* spa_w1   = (const float*)d_in[19];
  const float* spa_w2   = (const float*)d_in[20];
  const float* spa_lin  = (const float*)d_in[21];
  const float* imp_w0   = (const float*)d_in[22];
  const float* imp_b0   = (const float*)d_in[23];
  const float* imp_w1   = (const float*)d_in[24];
  const float* imp_b1   = (const float*)d_in[25];
  const float* imp_w2   = (const float*)d_in[26];
  const float* imp_b2   = (const float*)d_in[27];

  float* pe25  = ws + PE25_;  float* pe24 = ws + PE24_;  float* spa_pe = ws + SPAPE_;
  float* petok = ws + PETOK_; float* X = ws + X_;
  float* buf = ws + BUF_;   float* blk = ws + BLK_;   float* atok = ws + ATOK_;
  float* stok = ws + STOK_; float* stok2 = ws + STOK2_; float* tn = ws + TN_;
  float* ao = ws + AO_;     float* hb = ws + HB_;     float* qkv = ws + QKV_;
  float* t0 = ws + T0_;     float* t1 = ws + T1_;
  float* inp = ws + INP_;   float* h0 = ws + H0_;     float* h1 = ws + H1_;
  float* o2 = ws + O2_;

  const int BIG = 1 << 30;

  pe_tables_k<<<13, 256, 0, stream>>>(pe25, pe24);
  spa_pe_k<<<144, 256, 0, stream>>>(pe24, spa_pe);
  rearr_k<<<57, 256, 0, stream>>>(lr, X);

  // conv0 (1->64), 3x convi (64->64 lrelu), residual into buf. token-major out.
  conv3x3_k<<<1200, 64, 48*4, stream>>>(X, 576, 0, 1, conv0_w,
      nullptr, 0, 0, 0, buf, 36864, 1, 64, 1, 64, 0);
  conv3x3_k<<<1200, 64, 64*48*4, stream>>>(buf, 36864, 1, 64, convi_w,
      nullptr, 0, 0, 0, t0, 36864, 1, 64, 64, 64, 1);
  conv3x3_k<<<1200, 64, 64*48*4, stream>>>(t0, 36864, 1, 64, convi_w + 64*64*9,
      nullptr, 0, 0, 0, t1, 36864, 1, 64, 64, 64, 1);
  conv3x3_k<<<1200, 64, 64*48*4, stream>>>(t1, 36864, 1, 64, convi_w + 2*64*64*9,
      buf, 36864, 1, 64, buf, 36864, 1, 64, 64, 64, 2);

  for (int l = 0; l < 4; ++l) {
    const float* blkr = (l == 0) ? buf : blk;
    // ---- AngTrans ----
    ln_k<<<3600, 256, 0, stream>>>(blkr, pe25, 0, ang_ln_g + l*64, ang_ln_b + l*64, tn, 64);
    gemm_k<<<dim3(6, 450), 256, 0, stream>>>(tn, blkr, 128, ang_in + l*192*64,
        nullptr, nullptr, qkv, 14400, 192, 64, 0);
    attn_ang_k<<<576, 256, 0, stream>>>(qkv, ao);
    gemm_k<<<dim3(2, 450), 256, 0, stream>>>(ao, ao, BIG, ang_out + l*64*64,
        nullptr, blkr, atok, 14400, 64, 64, 0);
    ln_k<<<3600, 256, 0, stream>>>(atok, nullptr, -1, ang_ff_g + l*64, ang_ff_b + l*64, tn, 64);
    gemm_k<<<dim3(4, 450), 256, 0, stream>>>(tn, tn, BIG, ang_w1 + l*128*64,
        nullptr, nullptr, hb, 14400, 128, 64, 1);
    gemm_k<<<dim3(2, 450), 256, 0, stream>>>(hb, hb, BIG, ang_w2 + l*64*128,
        nullptr, atok, atok, 14400, 64, 128, 0);
    // ---- SpaTrans ----
    conv3x3_k<<<48, 128, 64*48*4, stream>>>(spa_pe, 0, 1, 64, spa_mlp + l*128*576,
        nullptr, 0, 0, 0, petok, 0, 1, 128, 64, 128, 0);
    conv3x3_k<<<1200, 128, 64*48*4, stream>>>(atok, 36864, 1, 64, spa_mlp + l*128*576,
        nullptr, 0, 0, 0, stok, 73728, 1, 128, 64, 128, 0);
    ln_k<<<3600, 256, 0, stream>>>(stok, petok, 1, spa_ln_g + l*128, spa_ln_b + l*128, tn, 128);
    gemm_k<<<dim3(12, 450), 256, 0, stream>>>(tn, stok, 256, spa_in + l*384*128,
        nullptr, nullptr, qkv, 14400, 384, 128, 0);
    attn_spa_k<<<450, 256, 0, stream>>>(qkv, ao);
    gemm_k<<<dim3(4, 450), 256, 0, stream>>>(ao, ao, BIG, spa_out + l*128*128,
        nullptr, stok, stok2, 14400, 128, 128, 0);
    ln_k<<<3600, 256, 0, stream>>>(stok2, nullptr, -1, spa_ff_g + l*128, spa_ff_b + l*128, tn, 128);
    gemm_k<<<dim3(8, 450), 256, 0, stream>>>(tn, tn, BIG, spa_w1 + l*256*128,
        nullptr, nullptr, hb, 14400, 256, 128, 1);
    gemm_k<<<dim3(4, 450), 256, 0, stream>>>(hb, hb, BIG, spa_w2 + l*128*256,
        nullptr, stok2, stok2, 14400, 128, 256, 0);
    gemm_k<<<dim3(2, 450), 256, 0, stream>>>(stok2, stok2, BIG, spa_lin + l*64*128,
        nullptr, nullptr, blk, 14400, 64, 128, 0);
  }

  add_k<<<3600, 256, 0, stream>>>(buf, blk, 921600);
  build_inp_k<<<14868, 256, 0, stream>>>(buf, coord, inp);
  gemm_k<<<dim3(10, 72), 256, 0, stream>>>(inp, inp, BIG, imp_w0, imp_b0, nullptr,
      h0, 2304, 320, 1652, 1);
  gemm_k<<<dim3(10, 72), 256, 0, stream>>>(h0, h0, BIG, imp_w1, imp_b1, nullptr,
      h1, 2304, 320, 320, 1);
  gemm_k<<<dim3(3, 72), 256, 0, stream>>>(h1, h1, BIG, imp_w2, imp_b2, nullptr,
      o2, 2304, 75, 320, 0);
  out_rearr_k<<<675, 256, 0, stream>>>(o2, (float*)d_out);
}

// Round 3
// 1111.558 us; speedup vs baseline: 2.5865x; 1.3169x over previous
//
#include <hip/hip_runtime.h>
#include <math.h>

typedef short  s16x4 __attribute__((ext_vector_type(4)));
typedef short  s16x8 __attribute__((ext_vector_type(8)));
typedef float  f32x4 __attribute__((ext_vector_type(4)));

// ---------------- workspace float offsets ----------------
static const size_t PE25_  = 0;         // 25*64
static const size_t PE24_  = 2048;      // 24*64
static const size_t SPAPE_ = 4096;      // [576][64]
static const size_t X_     = 40960;     // [25][576]
static const size_t PETOK_ = 55360;     // [576][128]
static const size_t W9C_   = 129088;    // [3][9][64][64]
static const size_t W9S_   = 239680;    // [4][9][128][64]
static const size_t BUF_   = 534592;    // [14400][64]
static const size_t BLK_   = 1456192;   // [14400][64]
static const size_t ATOK_  = 2377792;   // [14400][64]
static const size_t STOK_  = 3299392;   // [14400][128]
static const size_t STOK2_ = 5142592;   // [14400][128]
static const size_t TN_    = 6985792;   // [14400][128]
static const size_t AO_    = 8828992;   // [14400][128]
static const size_t QKV_   = 10672192;  // [14400][384]; aliases: t0,t1, hb, inp
static const size_t WS_FLOATS = 16201792;
static const size_t T0_  = QKV_;
static const size_t T1_  = QKV_ + 921600;
static const size_t HB_  = QKV_;        // [14400][256]
static const size_t INP_ = QKV_;        // [2304][1652]
static const size_t H0_  = STOK_;       // [2304][320]
static const size_t H1_  = STOK2_;
static const size_t O2_  = TN_;         // [2304][75]

// ---------------- bf16 split helpers ----------------
__device__ inline ushort f2bf(float x) {
  unsigned u = __float_as_uint(x);
  u += 0x7fffu + ((u >> 16) & 1u);
  return (ushort)(u >> 16);
}
__device__ inline float bf2f(ushort h) { return __uint_as_float(((unsigned)h) << 16); }

// store 4 consecutive k-elements as hi-plane (p) and lo-plane (p+1024)
__device__ inline void store_split(char* p, f32x4 v) {
  s16x4 hi, lo;
  #pragma unroll
  for (int e = 0; e < 4; ++e) {
    float x = v[e];
    ushort h = f2bf(x);
    ushort l = f2bf(x - bf2f(h));
    hi[e] = (short)h; lo[e] = (short)l;
  }
  *(s16x4*)p = hi;
  *(s16x4*)(p + 1024) = lo;
}

// MFMA core: 2 k-slices of 32, wave computes 32x32 (2x2 subtiles), 3-term split
__device__ inline void mfma_step(const char* ldsA, const char* ldsB, int lane,
                                 int wr, int wc, f32x4 acc[2][2]) {
  #pragma unroll
  for (int ks = 0; ks < 2; ++ks) {
    s16x8 ah[2], al[2], bh[2], bl[2];
    #pragma unroll
    for (int i = 0; i < 2; ++i) {
      const char* pa = ldsA + (((wr*2 + i)*2 + ks) << 11) + (lane << 4);
      ah[i] = *(const s16x8*)pa;
      al[i] = *(const s16x8*)(pa + 1024);
      const char* pb = ldsB + (((wc*2 + i)*2 + ks) << 11) + (lane << 4);
      bh[i] = *(const s16x8*)pb;
      bl[i] = *(const s16x8*)(pb + 1024);
    }
    #pragma unroll
    for (int i = 0; i < 2; ++i) {
      #pragma unroll
      for (int j = 0; j < 2; ++j) {
        acc[i][j] = __builtin_amdgcn_mfma_f32_16x16x32_bf16(ah[i], bh[j], acc[i][j], 0, 0, 0);
        acc[i][j] = __builtin_amdgcn_mfma_f32_16x16x32_bf16(ah[i], bl[j], acc[i][j], 0, 0, 0);
        acc[i][j] = __builtin_amdgcn_mfma_f32_16x16x32_bf16(al[i], bh[j], acc[i][j], 0, 0, 0);
      }
    }
  }
}

// epilogue: C/D layout col=lane&15, row=(lane>>4)*4+r (guide-verified)
__device__ inline void epilogue(f32x4 acc[2][2], const float* bias, const float* res,
                                float* out, int N, int m0, int n0,
                                int wr, int wc, int lane, int act) {
  int colb = n0 + wc*32 + (lane & 15);
  int rowb = m0 + wr*32 + ((lane >> 4) << 2);
  #pragma unroll
  for (int j = 0; j < 2; ++j) {
    int cc = colb + j*16;
    if (cc >= N) continue;
    float bv = bias ? bias[cc] : 0.f;
    #pragma unroll
    for (int i = 0; i < 2; ++i) {
      #pragma unroll
      for (int r = 0; r < 4; ++r) {
        int rr = rowb + i*16 + r;
        float v = acc[i][j][r] + bv;
        if (act == 1) v = fmaxf(v, 0.f);
        else if (act == 2) v = v > 0.f ? v : 0.2f*v;
        if (res) v += res[(long)rr*N + cc];
        out[(long)rr*N + cc] = v;
      }
    }
  }
}

// ---------------- MFMA GEMM: out = act(A @ W^T + bias) (+res) ----------------
// A,A2 [M][K] f32 row-major (A2 used when n0>=nsplit); W [N][K]; out,res [M][N]
// M%64==0, K%4==0 required.
__global__ __launch_bounds__(256) void mgemm_k(
    const float* __restrict__ A, const float* __restrict__ A2, int nsplit,
    const float* __restrict__ W, const float* __restrict__ bias,
    const float* __restrict__ res, float* __restrict__ out,
    int N, int K, int act) {
  __shared__ float ldsf[8192];
  char* ldsA = (char*)ldsf;
  char* ldsB = ldsA + 16384;
  int n0 = blockIdx.x * 64, m0 = blockIdx.y * 64;
  const float* Ap = (n0 >= nsplit) ? A2 : A;
  int t = threadIdx.x, lane = t & 63, wave = t >> 6;
  int wr = wave >> 1, wc = wave & 1;
  int rsub = (lane >> 1) & 15;
  int ksub = ((lane >> 5) << 3) + ((lane & 1) << 2);
  f32x4 acc[2][2];
  #pragma unroll
  for (int i = 0; i < 2; ++i)
    #pragma unroll
    for (int j = 0; j < 2; ++j)
      acc[i][j] = (f32x4){0.f, 0.f, 0.f, 0.f};
  for (int k0 = 0; k0 < K; k0 += 64) {
    __syncthreads();
    #pragma unroll
    for (int i = 0; i < 4; ++i) {
      int idx = (i << 2) + wave;
      int msub = idx >> 2, ks = (idx >> 1) & 1, kh = idx & 1;
      int row = (msub << 4) + rsub;
      int kof = (ks << 5) + (kh << 4) + ksub;
      int gk = k0 + kof;
      long wo = (long)((msub*2 + ks) << 11) + (kh << 9) + (lane << 3);
      f32x4 av = {0.f, 0.f, 0.f, 0.f};
      if (gk < K) av = *(const f32x4*)&Ap[(long)(m0 + row) * K + gk];
      store_split(ldsA + wo, av);
      f32x4 bv = {0.f, 0.f, 0.f, 0.f};
      if (gk < K && (n0 + row) < N) bv = *(const f32x4*)&W[(long)(n0 + row) * K + gk];
      store_split(ldsB + wo, bv);
    }
    __syncthreads();
    mfma_step(ldsA, ldsB, lane, wr, wc, acc);
  }
  epilogue(acc, bias, res, out, N, m0, n0, wr, wc, lane, act);
}

// ---------------- MFMA 3x3 conv as 9 shifted GEMMs ----------------
// in [Mtok][64] token-major (views of 24x24, 576 tokens each); W9 [9][N][64]
__global__ __launch_bounds__(256) void cgemm_k(
    const float* __restrict__ in, const float* __restrict__ W9,
    const float* __restrict__ res, float* __restrict__ out, int N, int act) {
  __shared__ float ldsf[8192];
  char* ldsA = (char*)ldsf;
  char* ldsB = ldsA + 16384;
  int n0 = blockIdx.x * 64, m0 = blockIdx.y * 64;
  int t = threadIdx.x, lane = t & 63, wave = t >> 6;
  int wr = wave >> 1, wc = wave & 1;
  int rsub = (lane >> 1) & 15;
  int ksub = ((lane >> 5) << 3) + ((lane & 1) << 2);
  f32x4 acc[2][2];
  #pragma unroll
  for (int i = 0; i < 2; ++i)
    #pragma unroll
    for (int j = 0; j < 2; ++j)
      acc[i][j] = (f32x4){0.f, 0.f, 0.f, 0.f};
  for (int ij = 0; ij < 9; ++ij) {
    int di = ij / 3 - 1, dj = ij % 3 - 1;
    __syncthreads();
    #pragma unroll
    for (int i = 0; i < 4; ++i) {
      int idx = (i << 2) + wave;
      int msub = idx >> 2, ks = (idx >> 1) & 1, kh = idx & 1;
      int row = (msub << 4) + rsub;
      int kof = (ks << 5) + (kh << 4) + ksub;
      long wo = (long)((msub*2 + ks) << 11) + (kh << 9) + (lane << 3);
      int tok = m0 + row;
      int hw = tok % 576;
      int h2 = hw / 24 + di, w2 = hw % 24 + dj;
      f32x4 av = {0.f, 0.f, 0.f, 0.f};
      if ((unsigned)h2 < 24u && (unsigned)w2 < 24u)
        av = *(const f32x4*)&in[(long)(tok - hw + h2*24 + w2) * 64 + kof];
      store_split(ldsA + wo, av);
      f32x4 bv = *(const f32x4*)&W9[((long)ij * N + n0 + row) * 64 + kof];
      store_split(ldsB + wo, bv);
    }
    __syncthreads();
    mfma_step(ldsA, ldsB, lane, wr, wc, acc);
  }
  epilogue(acc, nullptr, res, out, N, m0, n0, wr, wc, lane, act);
}

// ---------------- weight reorder: W9[ij][o][c] ----------------
__global__ void w9c_k(const float* __restrict__ cw, float* __restrict__ w9) {
  int g = blockIdx.x * 256 + threadIdx.x;
  if (g >= 3*9*64*64) return;
  int cv = g / 36864, rem = g % 36864;
  int ij = rem / 4096, oc = rem % 4096;
  int o = oc >> 6, c = oc & 63;
  w9[g] = cw[((long)(cv*64 + o)*64 + c)*9 + ij];
}
__global__ void w9s_k(const float* __restrict__ sm, float* __restrict__ w9) {
  int g = blockIdx.x * 256 + threadIdx.x;
  if (g >= 4*9*128*64) return;
  int l = g / 73728, rem = g % 73728;
  int ij = rem / 8192, oc = rem % 8192;
  int o = oc >> 6, c = oc & 63;
  w9[g] = sm[((long)(l*128 + o))*576 + c*9 + ij];
}

// ---------------- setup ----------------
__device__ inline float pe_val(int pos, int c) {
  int j = c & 31;
  float freq = powf(10000.f, -2.f * (float)j / 64.f);
  float arg = (float)pos * freq;
  return (c < 32) ? sinf(arg) : cosf(arg);
}

__global__ void pe_tables_k(float* pe25, float* pe24) {
  int g = blockIdx.x * 256 + threadIdx.x;
  if (g < 25*64) pe25[g] = pe_val(g / 64, g & 63);
  else if (g < 25*64 + 24*64) { int q = g - 25*64; pe24[q] = pe_val(q / 64, q & 63); }
}

__global__ void spa_pe_k(const float* __restrict__ pe24, float* __restrict__ spa_pe) {
  int g = blockIdx.x * 256 + threadIdx.x;
  if (g >= 576*64) return;
  int hw = g >> 6, c = g & 63; int h = hw / 24, w = hw % 24;
  spa_pe[g] = 0.5f * (pe24[h*64 + c] + pe24[w*64 + c]);
}

__global__ void rearr_k(const float* __restrict__ lr, float* __restrict__ X) {
  int g = blockIdx.x * 256 + threadIdx.x;
  if (g >= 14400) return;
  int a = g / 576, hw = g % 576, h = hw / 24, w = hw % 24;
  int a1 = a / 5, a2 = a % 5;
  X[g] = lr[(a1*24 + h)*120 + a2*24 + w];
}

// ---------------- conv0: 1->64, token-major out ----------------
__global__ void conv0_k(const float* __restrict__ X, const float* __restrict__ W,
                        float* __restrict__ out) {
  int bq = blockIdx.x;
  int a = bq / 48, r = bq % 48, h = r >> 1, w0 = (r & 1) * 12;
  __shared__ float patch[3][16];
  int t = threadIdx.x;
  if (t < 42) {
    int i = t / 14, col = t % 14;
    int h2 = h + i - 1, w2 = w0 + col - 1;
    float v = 0.f;
    if ((unsigned)h2 < 24u && (unsigned)w2 < 24u) v = X[a*576 + h2*24 + w2];
    patch[i][col] = v;
  }
  __syncthreads();
  float wv[9];
  #pragma unroll
  for (int q = 0; q < 9; ++q) wv[q] = W[t*9 + q];
  #pragma unroll
  for (int p = 0; p < 12; ++p) {
    float acc = 0.f;
    #pragma unroll
    for (int i = 0; i < 3; ++i)
      #pragma unroll
      for (int j = 0; j < 3; ++j)
        acc = fmaf(patch[i][p + j], wv[i*3 + j], acc);
    out[(long)(a*576 + h*24 + w0 + p)*64 + t] = acc;
  }
}

// ---------------- layernorm (+optional PE), wave per token ----------------
__global__ void ln_k(const float* __restrict__ in, const float* __restrict__ pe,
                     int pe_mode, const float* __restrict__ g, const float* __restrict__ b,
                     float* __restrict__ outp, int D) {
  int x = blockIdx.x * 4 + (threadIdx.x >> 6);
  int lane = threadIdx.x & 63;
  int E = D >> 6;
  float v[2]; float s = 0.f, s2 = 0.f;
  int pidx = (pe_mode == 0) ? (x / 576) : (x % 576);
  for (int e = 0; e < E; ++e) {
    int c = e*64 + lane;
    float t = in[(long)x*D + c];
    if (pe_mode >= 0) t += pe[(long)pidx*D + c];
    v[e] = t; s += t; s2 = fmaf(t, t, s2);
  }
  #pragma unroll
  for (int off = 32; off; off >>= 1) {
    s += __shfl_xor(s, off, 64); s2 += __shfl_xor(s2, off, 64);
  }
  float mean = s / D;
  float var = s2 / D - mean*mean;
  float rs = rsqrtf(var + 1e-5f);
  for (int e = 0; e < E; ++e) {
    int c = e*64 + lane;
    outp[(long)x*D + c] = (v[e] - mean) * rs * g[c] + b[c];
  }
}

// ---------------- angular attention (seq=25, nh=8, dh=8) ----------------
__global__ void attn_ang_k(const float* __restrict__ qkv, float* __restrict__ ao) {
  int hw = blockIdx.x;
  __shared__ float lds[25*192];
  for (int idx = threadIdx.x; idx < 25*192; idx += 256) {
    int a = idx / 192, c = idx % 192;
    lds[idx] = qkv[(long)(a*576 + hw)*192 + c];
  }
  __syncthreads();
  int t = threadIdx.x;
  if (t >= 200) return;
  int l = t / 8, head = t & 7;
  const float* q = lds + l*192 + head*8;
  float s[25]; float mx = -1e30f;
  #pragma unroll
  for (int m = 0; m < 25; ++m) {
    const float* kk = lds + m*192 + 64 + head*8;
    float acc = 0.f;
    #pragma unroll
    for (int d = 0; d < 8; ++d) acc = fmaf(q[d], kk[d], acc);
    acc *= 0.3535533905932738f;
    s[m] = acc; mx = fmaxf(mx, acc);
  }
  float sum = 0.f;
  #pragma unroll
  for (int m = 0; m < 25; ++m) { s[m] = expf(s[m] - mx); sum += s[m]; }
  float inv = 1.f / sum;
  #pragma unroll
  for (int d = 0; d < 8; ++d) {
    float acc = 0.f;
    #pragma unroll
    for (int m = 0; m < 25; ++m) acc = fmaf(s[m], lds[m*192 + 128 + head*8 + d], acc);
    ao[(long)(l*576 + hw)*64 + head*8 + d] = acc * inv;
  }
}

// ---------------- spatial attention (5x5 window, nh=8, dh=16) ----------------
__global__ void attn_spa_k(const float* __restrict__ qkv, float* __restrict__ ao) {
  int g = blockIdx.x * 256 + threadIdx.x;
  if (g >= 14400*8) return;
  int head = g & 7; int x = g >> 3;
  int a = x / 576, hw = x % 576, h = hw / 24, w = hw % 24;
  float qr[16];
  const float* qp = qkv + (long)x*384 + head*16;
  #pragma unroll
  for (int d = 0; d < 16; ++d) qr[d] = qp[d];
  float s[25]; float mx = -1e30f;
  #pragma unroll
  for (int i = 0; i < 25; ++i) {
    int h2 = h + i/5 - 2, w2 = w + i%5 - 2;
    float sc = -1e30f;
    if (h2 >= 0 && h2 < 24 && w2 >= 0 && w2 < 24) {
      const float* kp = qkv + (long)(a*576 + h2*24 + w2)*384 + 128 + head*16;
      sc = 0.f;
      #pragma unroll
      for (int d = 0; d < 16; ++d) sc = fmaf(qr[d], kp[d], sc);
      sc *= 0.25f;
    }
    s[i] = sc; mx = fmaxf(mx, sc);
  }
  float sum = 0.f;
  #pragma unroll
  for (int i = 0; i < 25; ++i) {
    float e = (s[i] > -1e29f) ? expf(s[i] - mx) : 0.f;
    s[i] = e; sum += e;
  }
  float inv = 1.f / sum;
  float acc[16];
  #pragma unroll
  for (int d = 0; d < 16; ++d) acc[d] = 0.f;
  #pragma unroll
  for (int i = 0; i < 25; ++i) {
    if (s[i] > 0.f) {
      int h2 = h + i/5 - 2, w2 = w + i%5 - 2;
      const float* vp = qkv + (long)(a*576 + h2*24 + w2)*384 + 256 + head*16;
      #pragma unroll
      for (int d = 0; d < 16; ++d) acc[d] = fmaf(s[i], vp[d], acc[d]);
    }
  }
  float* op = ao + (long)x*128 + head*16;
  #pragma unroll
  for (int d = 0; d < 16; ++d) op[d] = acc[d] * inv;
}

__global__ void add_k(float* __restrict__ a, const float* __restrict__ b, int n) {
  int g = blockIdx.x * 256 + threadIdx.x;
  if (g < n) a[g] += b[g];
}

// ---------------- upsample + concat -> imp MLP input ----------------
__global__ void build_inp_k(const float* __restrict__ buf, const float* __restrict__ coord,
                            float* __restrict__ inp) {
  long g = (long)blockIdx.x * 256 + threadIdx.x;
  if (g >= 2304L*1652) return;
  int p = (int)(g / 1652); int k = (int)(g % 1652);
  int hh = p / 48, ww = p % 48;
  float v;
  if (k < 1600) {
    int a = k >> 6, c = k & 63;
    float sh = hh*0.5f - 0.25f; float sw = ww*0.5f - 0.25f;
    int h0 = (int)floorf(sh); float fh = sh - h0;
    int w0 = (int)floorf(sw); float fw = sw - w0;
    int h0c = max(h0, 0), h1c = min(h0 + 1, 23);
    int w0c = max(w0, 0), w1c = min(w0 + 1, 23);
    long base = (long)a*576;
    float v00 = buf[(base + h0c*24 + w0c)*64 + c], v01 = buf[(base + h0c*24 + w1c)*64 + c];
    float v10 = buf[(base + h1c*24 + w0c)*64 + c], v11 = buf[(base + h1c*24 + w1c)*64 + c];
    v = (1.f - fh)*((1.f - fw)*v00 + fw*v01) + fh*((1.f - fw)*v10 + fw*v11);
  } else if (k < 1602) {
    int d = k - 1600;
    float co = coord[p*2 + d];
    float cc = fminf(fmaxf(co + 1e-6f, -1.f + 1e-6f), 1.f - 1e-6f);
    float ix = rintf(((cc + 1.f)*24.f - 1.f)*0.5f);
    ix = fminf(fmaxf(ix, 0.f), 23.f);
    float q = -1.f + (2.f*ix + 1.f)/24.f;
    v = (co - q)*24.f;
  } else {
    int idx = k - 1602; int pair = idx >> 1; int t = idx & 1;
    int i = pair / 5, j = pair % 5;
    v = 0.5f + (float)(t ? j : i);
  }
  inp[g] = v;
}

__global__ void out_rearr_k(const float* __restrict__ o2, float* __restrict__ out) {
  int g = blockIdx.x * 256 + threadIdx.x;
  if (g >= 172800) return;
  int ch = g / 57600; int r = g % 57600;
  int row = r / 240, col = r % 240;
  int a1 = row / 48, hh = row % 48, a2 = col / 48, ww = col % 48;
  out[g] = o2[(hh*48 + ww)*75 + (a1*5 + a2)*3 + ch];
}

// ---------------- host launch ----------------
extern "C" void kernel_launch(void* const* d_in, const int* in_sizes, int n_in,
                              void* d_out, int out_size, void* d_ws, size_t ws_size,
                              hipStream_t stream) {
  (void)in_sizes; (void)n_in; (void)out_size;
  if (ws_size < (size_t)WS_FLOATS * 4) return;
  float* ws = (float*)d_ws;

  const float* lr       = (const float*)d_in[0];
  const float* coord    = (const float*)d_in[1];
  const float* conv0_w  = (const float*)d_in[2];
  const float* convi_w  = (const float*)d_in[3];
  const float* ang_ln_g = (const float*)d_in[4];
  const float* ang_ln_b = (const float*)d_in[5];
  const float* ang_in   = (const float*)d_in[6];
  const float* ang_out  = (const float*)d_in[7];
  const float* ang_ff_g = (const float*)d_in[8];
  const float* ang_ff_b = (const float*)d_in[9];
  const float* ang_w1   = (const float*)d_in[10];
  const float* ang_w2   = (const float*)d_in[11];
  const float* spa_mlp  = (const float*)d_in[12];
  const float* spa_ln_g = (const float*)d_in[13];
  const float* spa_ln_b = (const float*)d_in[14];
  const float* spa_in   = (const float*)d_in[15];
  const float* spa_out  = (const float*)d_in[16];
  const float* spa_ff_g = (const float*)d_in[17];
  const float* spa_ff_b = (const float*)d_in[18];
  const float* spa_w1   = (const float*)d_in[19];
  const float* spa_w2   = (const float*)d_in[20];
  const float* spa_lin  = (const float*)d_in[21];
  const float* imp_w0   = (const float*)d_in[22];
  const float* imp_b0   = (const float*)d_in[23];
  const float* imp_w1   = (const float*)d_in[24];
  const float* imp_b1   = (const float*)d_in[25];
  const float* imp_w2   = (const float*)d_in[26];
  const float* imp_b2   = (const float*)d_in[27];

  float* pe25  = ws + PE25_;  float* pe24 = ws + PE24_;  float* spa_pe = ws + SPAPE_;
  float* X = ws + X_;         float* petok = ws + PETOK_;
  float* w9c = ws + W9C_;     float* w9s = ws + W9S_;
  float* buf = ws + BUF_;     float* blk = ws + BLK_;    float* atok = ws + ATOK_;
  float* stok = ws + STOK_;   float* stok2 = ws + STOK2_; float* tn = ws + TN_;
  float* ao = ws + AO_;       float* qkv = ws + QKV_;
  float* t0 = ws + T0_;       float* t1 = ws + T1_;      float* hb = ws + HB_;
  float* inp = ws + INP_;     float* h0 = ws + H0_;      float* h1 = ws + H1_;
  float* o2 = ws + O2_;

  const int BIG = 1 << 30;

  pe_tables_k<<<13, 256, 0, stream>>>(pe25, pe24);
  spa_pe_k<<<144, 256, 0, stream>>>(pe24, spa_pe);
  rearr_k<<<57, 256, 0, stream>>>(lr, X);
  w9c_k<<<432, 256, 0, stream>>>(convi_w, w9c);
  w9s_k<<<1152, 256, 0, stream>>>(spa_mlp, w9s);

  conv0_k<<<1200, 64, 0, stream>>>(X, conv0_w, buf);
  cgemm_k<<<dim3(1, 225), 256, 0, stream>>>(buf, w9c,           nullptr, t0,  64, 2);
  cgemm_k<<<dim3(1, 225), 256, 0, stream>>>(t0,  w9c + 36864,   nullptr, t1,  64, 2);
  cgemm_k<<<dim3(1, 225), 256, 0, stream>>>(t1,  w9c + 73728,   buf,     buf, 64, 2);

  for (int l = 0; l < 4; ++l) {
    const float* blkr = (l == 0) ? buf : blk;
    // ---- AngTrans ----
    ln_k<<<3600, 256, 0, stream>>>(blkr, pe25, 0, ang_ln_g + l*64, ang_ln_b + l*64, tn, 64);
    mgemm_k<<<dim3(3, 225), 256, 0, stream>>>(tn, blkr, 128, ang_in + l*192*64,
        nullptr, nullptr, qkv, 192, 64, 0);
    attn_ang_k<<<576, 256, 0, stream>>>(qkv, ao);
    mgemm_k<<<dim3(1, 225), 256, 0, stream>>>(ao, ao, BIG, ang_out + l*64*64,
        nullptr, blkr, atok, 64, 64, 0);
    ln_k<<<3600, 256, 0, stream>>>(atok, nullptr, -1, ang_ff_g + l*64, ang_ff_b + l*64, tn, 64);
    mgemm_k<<<dim3(2, 225), 256, 0, stream>>>(tn, tn, BIG, ang_w1 + l*128*64,
        nullptr, nullptr, hb, 128, 64, 1);
    mgemm_k<<<dim3(1, 225), 256, 0, stream>>>(hb, hb, BIG, ang_w2 + l*64*128,
        nullptr, atok, atok, 64, 128, 0);
    // ---- SpaTrans ----
    cgemm_k<<<dim3(2, 9), 256, 0, stream>>>(spa_pe, w9s + l*73728, nullptr, petok, 128, 0);
    cgemm_k<<<dim3(2, 225), 256, 0, stream>>>(atok, w9s + l*73728, nullptr, stok, 128, 0);
    ln_k<<<3600, 256, 0, stream>>>(stok, petok, 1, spa_ln_g + l*128, spa_ln_b + l*128, tn, 128);
    mgemm_k<<<dim3(6, 225), 256, 0, stream>>>(tn, stok, 256, spa_in + l*384*128,
        nullptr, nullptr, qkv, 384, 128, 0);
    attn_spa_k<<<450, 256, 0, stream>>>(qkv, ao);
    mgemm_k<<<dim3(2, 225), 256, 0, stream>>>(ao, ao, BIG, spa_out + l*128*128,
        nullptr, stok, stok2, 128, 128, 0);
    ln_k<<<3600, 256, 0, stream>>>(stok2, nullptr, -1, spa_ff_g + l*128, spa_ff_b + l*128, tn, 128);
    mgemm_k<<<dim3(4, 225), 256, 0, stream>>>(tn, tn, BIG, spa_w1 + l*256*128,
        nullptr, nullptr, hb, 256, 128, 1);
    mgemm_k<<<dim3(2, 225), 256, 0, stream>>>(hb, hb, BIG, spa_w2 + l*128*256,
        nullptr, stok2, stok2, 128, 256, 0);
    mgemm_k<<<dim3(1, 225), 256, 0, stream>>>(stok2, stok2, BIG, spa_lin + l*64*128,
        nullptr, nullptr, blk, 64, 128, 0);
  }

  add_k<<<3600, 256, 0, stream>>>(buf, blk, 921600);
  build_inp_k<<<14868, 256, 0, stream>>>(buf, coord, inp);
  mgemm_k<<<dim3(5, 36), 256, 0, stream>>>(inp, inp, BIG, imp_w0, imp_b0, nullptr,
      h0, 320, 1652, 1);
  mgemm_k<<<dim3(5, 36), 256, 0, stream>>>(h0, h0, BIG, imp_w1, imp_b1, nullptr,
      h1, 320, 320, 1);
  mgemm_k<<<dim3(2, 36), 256, 0, stream>>>(h1, h1, BIG, imp_w2, imp_b2, nullptr,
      o2, 75, 320, 0);
  out_rearr_k<<<675, 256, 0, stream>>>(o2, (float*)d_out);
}